// Round 3
// baseline (824.200 us; speedup 1.0000x reference)
//
#include <hip/hip_runtime.h>

#define L_SEQ 2048
#define CDIM  512
#define NB    4
#define NH    8
#define DKH   64

typedef __attribute__((ext_vector_type(8))) __bf16 bf16x8;
typedef __attribute__((ext_vector_type(4))) float  f32x4;
typedef __attribute__((ext_vector_type(8))) unsigned short u16x8;

__device__ __forceinline__ unsigned short f2bf(float f) {
  union { float f; unsigned u; } x; x.f = f;
  unsigned r = x.u + 0x7FFFu + ((x.u >> 16) & 1u);
  return (unsigned short)(r >> 16);
}
__device__ __forceinline__ float bf2f(unsigned short u) {
  union { unsigned u; float f; } x; x.u = ((unsigned)u) << 16;
  return x.f;
}
__device__ __forceinline__ bf16x8 ldfrag(const unsigned short* p) {
  u16x8 v = *reinterpret_cast<const u16x8*>(p);
  return __builtin_bit_cast(bf16x8, v);
}
__device__ __forceinline__ float fexp2(float x) {
  float r; asm("v_exp_f32 %0, %1" : "=v"(r) : "v"(x)); return r;
}
#define MFMA(a,b,c) __builtin_amdgcn_mfma_f32_16x16x32_bf16((a),(b),(c),0,0,0)

#define GLOADLDS(gp, lp) __builtin_amdgcn_global_load_lds( \
    (const __attribute__((address_space(1))) void*)(gp),   \
    (__attribute__((address_space(3))) void*)(lp), 16, 0, 0)

// ---------------- elementwise f32 -> bf16 cast (for W matrices) ----------------
__global__ __launch_bounds__(256) void k_cast(const float* __restrict__ X,
                                              unsigned short* __restrict__ Y, int n) {
  int i = (blockIdx.x * 256 + threadIdx.x) * 8;
  if (i + 8 > n) return;
  const float4* p = reinterpret_cast<const float4*>(X + i);
  float4 a = p[0], b = p[1];
  u16x8 o;
  o[0]=f2bf(a.x); o[1]=f2bf(a.y); o[2]=f2bf(a.z); o[3]=f2bf(a.w);
  o[4]=f2bf(b.x); o[5]=f2bf(b.y); o[6]=f2bf(b.z); o[7]=f2bf(b.w);
  *reinterpret_cast<u16x8*>(Y + i) = o;
}

// ---------------- transpose+cast: X (B,C,L) f32 -> Xt (B,L,C) bf16 ----------------
__global__ __launch_bounds__(256) void k_transpose(const float* __restrict__ X,
                                                   unsigned short* __restrict__ Xt) {
  __shared__ __align__(16) unsigned short t[64][72];   // [l][c], padded stride 72
  int l0 = blockIdx.x * 64, c0 = blockIdx.y * 64;
  size_t boff = (size_t)blockIdx.z * CDIM * L_SEQ;
  const float* Xb = X + boff;
  unsigned short* Xtb = Xt + boff;
  int tid = threadIdx.x;
  int cc = tid >> 2, lo = (tid & 3) * 16;
  const float* src = Xb + (size_t)(c0 + cc) * L_SEQ + l0 + lo;
#pragma unroll
  for (int i = 0; i < 4; ++i) {
    float4 v = *reinterpret_cast<const float4*>(src + i * 4);
    t[lo + i*4 + 0][cc] = f2bf(v.x);
    t[lo + i*4 + 1][cc] = f2bf(v.y);
    t[lo + i*4 + 2][cc] = f2bf(v.z);
    t[lo + i*4 + 3][cc] = f2bf(v.w);
  }
  __syncthreads();
  int ll = tid >> 2, co = (tid & 3) * 16;
  unsigned short* dst = Xtb + (size_t)(l0 + ll) * CDIM + c0 + co;
  u16x8 a = *reinterpret_cast<const u16x8*>(&t[ll][co]);
  u16x8 b = *reinterpret_cast<const u16x8*>(&t[ll][co + 8]);
  *reinterpret_cast<u16x8*>(dst) = a;
  *reinterpret_cast<u16x8*>(dst + 8) = b;
}

// ---------------- NT GEMM: C[M][N] = scale * A(MxK) . Bt(NxK)^T (+bias[m]), K=512 ----------------
template<int OUT_BF16, int HAS_BIAS>
__global__ __launch_bounds__(256) void k_gemm_nt(
    const unsigned short* __restrict__ A, long sA,
    const unsigned short* __restrict__ Bt, long sB,
    void* __restrict__ Out, long sO,
    const float* __restrict__ bias, float scale, int M, int N) {
  __shared__ __align__(16) unsigned short lA[128 * 64];
  __shared__ __align__(16) unsigned short lB[128 * 64];
  int b = blockIdx.z;
  const unsigned short* Ab = A + (size_t)b * sA;
  const unsigned short* Bb = Bt + (size_t)b * sB;
  int m0 = blockIdx.y * 128, n0 = blockIdx.x * 128;
  int tid = threadIdx.x, lane = tid & 63, wave = tid >> 6;
  int wm = (wave >> 1) * 64, wn = (wave & 1) * 64;
  f32x4 acc[4][4] = {};
  int srow = tid >> 3;   // 0..31
  int sslot = tid & 7;   // 0..7

  for (int k0 = 0; k0 < 512; k0 += 64) {
    __syncthreads();
#pragma unroll
    for (int i = 0; i < 4; ++i) {
      int r = srow + 32 * i;
      int sw = (sslot ^ (r & 7)) * 8;
      u16x8 va = *reinterpret_cast<const u16x8*>(Ab + (size_t)(m0 + r) * 512 + k0 + sslot * 8);
      *reinterpret_cast<u16x8*>(&lA[r * 64 + sw]) = va;
      u16x8 vb = *reinterpret_cast<const u16x8*>(Bb + (size_t)(n0 + r) * 512 + k0 + sslot * 8);
      *reinterpret_cast<u16x8*>(&lB[r * 64 + sw]) = vb;
    }
    __syncthreads();
#pragma unroll
    for (int c = 0; c < 2; ++c) {
      bf16x8 af[4], bfr[4];
#pragma unroll
      for (int t = 0; t < 4; ++t) {
        int ra = wm + t * 16 + (lane & 15);
        int sa = (lane >> 4) + 4 * c;
        af[t] = ldfrag(&lA[ra * 64 + ((sa ^ (ra & 7)) * 8)]);
        int rb = wn + t * 16 + (lane & 15);
        bfr[t] = ldfrag(&lB[rb * 64 + ((sa ^ (rb & 7)) * 8)]);
      }
#pragma unroll
      for (int i = 0; i < 4; ++i)
#pragma unroll
        for (int j = 0; j < 4; ++j)
          acc[i][j] = MFMA(af[i], bfr[j], acc[i][j]);
    }
  }
  int row4 = (lane >> 4) * 4, col = lane & 15;
#pragma unroll
  for (int i = 0; i < 4; ++i)
#pragma unroll
    for (int j = 0; j < 4; ++j)
#pragma unroll
      for (int e = 0; e < 4; ++e) {
        int r = m0 + wm + i * 16 + row4 + e;
        int cN = n0 + wn + j * 16 + col;
        float v = acc[i][j][e] * scale;
        if (HAS_BIAS) v += bias[r];
        size_t idx = (size_t)b * sO + (size_t)r * N + cN;
        if (OUT_BF16) ((unsigned short*)Out)[idx] = f2bf(v);
        else          ((float*)Out)[idx] = v;
      }
}

// ---------------- fused attention: scores -> softmax -> A out + PV ----------------
// Qt,Kt: (B,L,512) bf16 (Q pre-scaled 0.125*log2e). Vn: (B,512,L) bf16.
// HhT out: (B,L,512) bf16. Aout: (B,H,L,L) f32.
// K and V tiles (64x64 bf16) staged cooperatively in LDS, double-buffered,
// XOR-swizzled via pre-swizzled global source addresses (global_load_lds is
// linear-dest). Softmax via 2^x (scale folded into Q).
__global__ __launch_bounds__(256) void k_attn(
    const unsigned short* __restrict__ Qt,
    const unsigned short* __restrict__ Kt,
    const unsigned short* __restrict__ Vn,
    unsigned short* __restrict__ HhT,
    float* __restrict__ Aout) {
  __shared__ __align__(16) unsigned short Kb[2][4096];
  __shared__ __align__(16) unsigned short Vb[2][4096];
  __shared__ __align__(16) unsigned short al[4][1024];
  int bh = blockIdx.y;
  int b = bh >> 3, h = bh & 7;
  int tid = threadIdx.x;
  int lane = tid & 63, wave = tid >> 6;
  int q0 = blockIdx.x * 64 + wave * 16;
  const unsigned short* Qh = Qt + (size_t)b * L_SEQ * CDIM + h * DKH;
  const unsigned short* Kh = Kt + (size_t)b * L_SEQ * CDIM + h * DKH;
  const unsigned short* Vh = Vn + (size_t)b * CDIM * L_SEQ + (size_t)h * DKH * L_SEQ;
  unsigned short* Ho = HhT + (size_t)b * L_SEQ * CDIM + h * DKH;
  float* Ab = Aout + (size_t)bh * L_SEQ * L_SEQ;

  int fr = lane & 15, fg = lane >> 4;
  bf16x8 qf0 = ldfrag(Qh + (size_t)(q0 + fr) * CDIM + fg * 8);
  bf16x8 qf1 = ldfrag(Qh + (size_t)(q0 + fr) * CDIM + fg * 8 + 32);

  // staging geometry: call c covers tile rows 8c..8c+7 (1KB of LDS).
  // lane -> LDS byte c*1024 + lane*16  == row (8c + lane>>3), phys slot (lane&7).
  // phys slot ps holds logical slot ps ^ (row&7)  => load global slot accordingly.
  int rowin = lane >> 3;               // 0..7
  int slot = (lane & 7) ^ rowin;       // logical 16B-slot to fetch
  int c0 = wave * 2, c1 = wave * 2 + 1;
  const unsigned short* gk0 = Kh + (size_t)(c0 * 8 + rowin) * CDIM + slot * 8;
  const unsigned short* gk1 = Kh + (size_t)(c1 * 8 + rowin) * CDIM + slot * 8;
  const unsigned short* gv0 = Vh + (size_t)(c0 * 8 + rowin) * L_SEQ + slot * 8;
  const unsigned short* gv1 = Vh + (size_t)(c1 * 8 + rowin) * L_SEQ + slot * 8;

#define STAGE_K(bi, ktoff) do { \
    GLOADLDS(gk0 + (size_t)(ktoff) * CDIM, &Kb[bi][c0 * 512]); \
    GLOADLDS(gk1 + (size_t)(ktoff) * CDIM, &Kb[bi][c1 * 512]); } while (0)
#define STAGE_V(bi, ktoff) do { \
    GLOADLDS(gv0 + (ktoff), &Vb[bi][c0 * 512]); \
    GLOADLDS(gv1 + (ktoff), &Vb[bi][c1 * 512]); } while (0)

  // -------- pass 1: row sums of 2^s --------
  float psum[4] = {0.f, 0.f, 0.f, 0.f};
  STAGE_K(0, 0);
  __syncthreads();
  int buf = 0;
  for (int i = 0; i < 32; ++i) {
    if (i < 31) STAGE_K(buf ^ 1, (i + 1) * 64);
    const unsigned short* kb = Kb[buf];
#pragma unroll
    for (int t = 0; t < 4; ++t) {
      int r = t * 16 + fr;
      bf16x8 kf0 = ldfrag(kb + r * 64 + ((fg ^ (r & 7)) * 8));
      bf16x8 kf1 = ldfrag(kb + r * 64 + (((fg + 4) ^ (r & 7)) * 8));
      f32x4 s = {0.f, 0.f, 0.f, 0.f};
      s = MFMA(qf0, kf0, s);
      s = MFMA(qf1, kf1, s);
#pragma unroll
      for (int e = 0; e < 4; ++e) psum[e] += fexp2(s[e]);
    }
    __syncthreads();
    buf ^= 1;
  }
#pragma unroll
  for (int e = 0; e < 4; ++e) {
    psum[e] += __shfl_xor(psum[e], 1, 64);
    psum[e] += __shfl_xor(psum[e], 2, 64);
    psum[e] += __shfl_xor(psum[e], 4, 64);
    psum[e] += __shfl_xor(psum[e], 8, 64);
  }
  float inv[4];
#pragma unroll
  for (int e = 0; e < 4; ++e) inv[e] = 1.0f / psum[e];

  // -------- pass 2: recompute, write A, accumulate PV --------
  f32x4 oacc[4] = {};
  unsigned short* alw = al[wave];
  STAGE_K(0, 0);
  STAGE_V(0, 0);
  __syncthreads();
  buf = 0;
  for (int i = 0; i < 32; ++i) {
    int kt = i * 64;
    if (i < 31) { STAGE_K(buf ^ 1, kt + 64); STAGE_V(buf ^ 1, kt + 64); }
    const unsigned short* kb = Kb[buf];
    const unsigned short* vb = Vb[buf];
    f32x4 sv[4];
#pragma unroll
    for (int t = 0; t < 4; ++t) {
      int r = t * 16 + fr;
      bf16x8 kf0 = ldfrag(kb + r * 64 + ((fg ^ (r & 7)) * 8));
      bf16x8 kf1 = ldfrag(kb + r * 64 + (((fg + 4) ^ (r & 7)) * 8));
      f32x4 s = {0.f, 0.f, 0.f, 0.f};
      s = MFMA(qf0, kf0, s);
      s = MFMA(qf1, kf1, s);
      sv[t] = s;
    }
    // A values -> swizzled per-wave LDS (bf16)
#pragma unroll
    for (int t = 0; t < 4; ++t)
#pragma unroll
      for (int e = 0; e < 4; ++e) {
        float a = fexp2(sv[t][e]) * inv[e];
        int row = fg * 4 + e;
        int byte = (row * 128 + (t * 16 + fr) * 2) ^ ((row & 7) << 4);
        alw[byte >> 1] = f2bf(a);
      }
    // coalesced non-temporal global A write from LDS
    {
      int wrow = lane >> 2;
      int slot0 = (lane & 3) * 2;
      int by0 = (wrow * 128 + slot0 * 16) ^ ((wrow & 7) << 4);
      int by1 = (wrow * 128 + (slot0 + 1) * 16) ^ ((wrow & 7) << 4);
      u16x8 p0 = *reinterpret_cast<const u16x8*>(alw + (by0 >> 1));
      u16x8 p1 = *reinterpret_cast<const u16x8*>(alw + (by1 >> 1));
      float* dp = Ab + (size_t)(q0 + wrow) * L_SEQ + kt + (lane & 3) * 16;
      f32x4 f0 = {bf2f(p0[0]), bf2f(p0[1]), bf2f(p0[2]), bf2f(p0[3])};
      f32x4 f1 = {bf2f(p0[4]), bf2f(p0[5]), bf2f(p0[6]), bf2f(p0[7])};
      f32x4 f2 = {bf2f(p1[0]), bf2f(p1[1]), bf2f(p1[2]), bf2f(p1[3])};
      f32x4 f3 = {bf2f(p1[4]), bf2f(p1[5]), bf2f(p1[6]), bf2f(p1[7])};
      __builtin_nontemporal_store(f0, reinterpret_cast<f32x4*>(dp + 0));
      __builtin_nontemporal_store(f1, reinterpret_cast<f32x4*>(dp + 4));
      __builtin_nontemporal_store(f2, reinterpret_cast<f32x4*>(dp + 8));
      __builtin_nontemporal_store(f3, reinterpret_cast<f32x4*>(dp + 12));
    }
    // PV: A-frags from LDS, V-frags from staged LDS tile
    int byA0 = (fr * 128 + fg * 16) ^ ((fr & 7) << 4);
    int byA1 = (fr * 128 + (fg + 4) * 16) ^ ((fr & 7) << 4);
    bf16x8 af0 = ldfrag(alw + (byA0 >> 1));
    bf16x8 af1 = ldfrag(alw + (byA1 >> 1));
#pragma unroll
    for (int nt = 0; nt < 4; ++nt) {
      int r = nt * 16 + fr;
      bf16x8 vf0 = ldfrag(vb + r * 64 + ((fg ^ (r & 7)) * 8));
      bf16x8 vf1 = ldfrag(vb + r * 64 + (((fg + 4) ^ (r & 7)) * 8));
      oacc[nt] = MFMA(af0, vf0, oacc[nt]);
      oacc[nt] = MFMA(af1, vf1, oacc[nt]);
    }
    __syncthreads();
    buf ^= 1;
  }
  // write HhT (B,L,512) bf16
#pragma unroll
  for (int nt = 0; nt < 4; ++nt)
#pragma unroll
    for (int e = 0; e < 4; ++e)
      Ho[(size_t)(q0 + fg * 4 + e) * CDIM + nt * 16 + fr] = f2bf(oacc[nt][e]);
#undef STAGE_K
#undef STAGE_V
}

extern "C" void kernel_launch(void* const* d_in, const int* in_sizes, int n_in,
                              void* d_out, int out_size, void* d_ws, size_t ws_size,
                              hipStream_t stream) {
  const float* Xq = (const float*)d_in[0];
  const float* Xk = (const float*)d_in[1];
  const float* Xv = (const float*)d_in[2];
  const float* Wq = (const float*)d_in[3];
  const float* Wk = (const float*)d_in[4];
  const float* Wv = (const float*)d_in[5];
  const float* Wh = (const float*)d_in[6];
  const float* bh = (const float*)d_in[7];

  const size_t PROJ = (size_t)NB * L_SEQ * CDIM;
  float* out_f = (float*)d_out;
  float* A_out = out_f + PROJ;

  unsigned short* Qt = (unsigned short*)d_out;
  unsigned short* Kt = Qt + PROJ;
  unsigned short* Xtq = (unsigned short*)A_out;
  unsigned short* Xtk = Xtq + PROJ;
  unsigned short* Xtv = Xtk + PROJ;
  unsigned short* Vn  = (unsigned short*)d_ws;
  unsigned short* HhT = Vn + PROJ;
  unsigned short* Wqb = HhT + PROJ;
  unsigned short* Wkb = Wqb + CDIM * CDIM;
  unsigned short* Wvb = Wkb + CDIM * CDIM;
  unsigned short* Whb = Wvb + CDIM * CDIM;

  int nW = CDIM * CDIM;
  k_cast<<<nW / 2048, 256, 0, stream>>>(Wq, Wqb, nW);
  k_cast<<<nW / 2048, 256, 0, stream>>>(Wk, Wkb, nW);
  k_cast<<<nW / 2048, 256, 0, stream>>>(Wv, Wvb, nW);
  k_cast<<<nW / 2048, 256, 0, stream>>>(Wh, Whb, nW);

  dim3 tg(L_SEQ / 64, CDIM / 64, NB);
  k_transpose<<<tg, 256, 0, stream>>>(Xq, Xtq);
  k_transpose<<<tg, 256, 0, stream>>>(Xk, Xtk);
  k_transpose<<<tg, 256, 0, stream>>>(Xv, Xtv);

  const long sLC = (long)L_SEQ * CDIM;
  // Qt = Xtq . Wq^T * (0.125 * log2(e))  -> softmax uses 2^x
  k_gemm_nt<1, 0><<<dim3(CDIM / 128, L_SEQ / 128, NB), 256, 0, stream>>>(
      Xtq, sLC, Wqb, 0, Qt, sLC, nullptr, 0.18033688f, L_SEQ, CDIM);
  k_gemm_nt<1, 0><<<dim3(CDIM / 128, L_SEQ / 128, NB), 256, 0, stream>>>(
      Xtk, sLC, Wkb, 0, Kt, sLC, nullptr, 1.0f, L_SEQ, CDIM);
  k_gemm_nt<1, 0><<<dim3(L_SEQ / 128, CDIM / 128, NB), 256, 0, stream>>>(
      Wvb, 0, Xtv, sLC, Vn, sLC, nullptr, 1.0f, CDIM, L_SEQ);

  k_attn<<<dim3(L_SEQ / 64, NB * NH), 256, 0, stream>>>(Qt, Kt, Vn, HhT, A_out);

  k_gemm_nt<0, 1><<<dim3(L_SEQ / 128, CDIM / 128, NB), 256, 0, stream>>>(
      Whb, 0, HhT, sLC, out_f, sLC, bh, 1.0f, CDIM, L_SEQ);
}

// Round 6
// 519.838 us; speedup vs baseline: 1.5855x; 1.5855x over previous
//
#include <hip/hip_runtime.h>

#define L_SEQ 2048
#define CDIM  512
#define NB    4
#define NH    8
#define DKH   64

typedef __attribute__((ext_vector_type(8))) __bf16 bf16x8;
typedef __attribute__((ext_vector_type(4))) float  f32x4;
typedef __attribute__((ext_vector_type(8))) unsigned short u16x8;

__device__ __forceinline__ unsigned short f2bf(float f) {
  union { float f; unsigned u; } x; x.f = f;
  unsigned r = x.u + 0x7FFFu + ((x.u >> 16) & 1u);
  return (unsigned short)(r >> 16);
}
__device__ __forceinline__ float bf2f(unsigned short u) {
  union { unsigned u; float f; } x; x.u = ((unsigned)u) << 16;
  return x.f;
}
__device__ __forceinline__ bf16x8 ldfrag(const unsigned short* p) {
  u16x8 v = *reinterpret_cast<const u16x8*>(p);
  return __builtin_bit_cast(bf16x8, v);
}
__device__ __forceinline__ bf16x8 asbf(u16x8 v) { return __builtin_bit_cast(bf16x8, v); }
__device__ __forceinline__ float fexp2(float x) {
  float r; asm("v_exp_f32 %0, %1" : "=v"(r) : "v"(x)); return r;
}
#define MFMA(a,b,c) __builtin_amdgcn_mfma_f32_16x16x32_bf16((a),(b),(c),0,0,0)

// load a 4-frag (64-row-chunk) K/V register set: base pre-offset by (fr,fg);
// frag t covers rows kt + t*16 + fr, 16B halves at +0 / +32 elements.
__device__ __forceinline__ void loadset(u16x8* dst, const unsigned short* base,
                                        int kt, long stride) {
#pragma unroll
  for (int t = 0; t < 4; ++t) {
    const unsigned short* p = base + (size_t)(kt + t * 16) * stride;
    dst[2*t]   = *reinterpret_cast<const u16x8*>(p);
    dst[2*t+1] = *reinterpret_cast<const u16x8*>(p + 32);
  }
}

// ---------------- elementwise f32 -> bf16 cast (for W matrices) ----------------
__global__ __launch_bounds__(256) void k_cast(const float* __restrict__ X,
                                              unsigned short* __restrict__ Y, int n) {
  int i = (blockIdx.x * 256 + threadIdx.x) * 8;
  if (i + 8 > n) return;
  const float4* p = reinterpret_cast<const float4*>(X + i);
  float4 a = p[0], b = p[1];
  u16x8 o;
  o[0]=f2bf(a.x); o[1]=f2bf(a.y); o[2]=f2bf(a.z); o[3]=f2bf(a.w);
  o[4]=f2bf(b.x); o[5]=f2bf(b.y); o[6]=f2bf(b.z); o[7]=f2bf(b.w);
  *reinterpret_cast<u16x8*>(Y + i) = o;
}

// ---------------- transpose+cast: X (B,C,L) f32 -> Xt (B,L,C) bf16 ----------------
__global__ __launch_bounds__(256) void k_transpose(const float* __restrict__ X,
                                                   unsigned short* __restrict__ Xt) {
  __shared__ __align__(16) unsigned short t[64][72];   // [l][c], padded stride 72
  int l0 = blockIdx.x * 64, c0 = blockIdx.y * 64;
  size_t boff = (size_t)blockIdx.z * CDIM * L_SEQ;
  const float* Xb = X + boff;
  unsigned short* Xtb = Xt + boff;
  int tid = threadIdx.x;
  int cc = tid >> 2, lo = (tid & 3) * 16;
  const float* src = Xb + (size_t)(c0 + cc) * L_SEQ + l0 + lo;
#pragma unroll
  for (int i = 0; i < 4; ++i) {
    float4 v = *reinterpret_cast<const float4*>(src + i * 4);
    t[lo + i*4 + 0][cc] = f2bf(v.x);
    t[lo + i*4 + 1][cc] = f2bf(v.y);
    t[lo + i*4 + 2][cc] = f2bf(v.z);
    t[lo + i*4 + 3][cc] = f2bf(v.w);
  }
  __syncthreads();
  int ll = tid >> 2, co = (tid & 3) * 16;
  unsigned short* dst = Xtb + (size_t)(l0 + ll) * CDIM + c0 + co;
  u16x8 a = *reinterpret_cast<const u16x8*>(&t[ll][co]);
  u16x8 b = *reinterpret_cast<const u16x8*>(&t[ll][co + 8]);
  *reinterpret_cast<u16x8*>(dst) = a;
  *reinterpret_cast<u16x8*>(dst + 8) = b;
}

// ---------------- NT GEMM: C[M][N] = scale * A(MxK) . Bt(NxK)^T (+bias[m]), K=512 ----------------
template<int OUT_BF16, int HAS_BIAS>
__global__ __launch_bounds__(256) void k_gemm_nt(
    const unsigned short* __restrict__ A, long sA,
    const unsigned short* __restrict__ Bt, long sB,
    void* __restrict__ Out, long sO,
    const float* __restrict__ bias, float scale, int M, int N) {
  __shared__ __align__(16) unsigned short lA[128 * 64];
  __shared__ __align__(16) unsigned short lB[128 * 64];
  int b = blockIdx.z;
  const unsigned short* Ab = A + (size_t)b * sA;
  const unsigned short* Bb = Bt + (size_t)b * sB;
  int m0 = blockIdx.y * 128, n0 = blockIdx.x * 128;
  int tid = threadIdx.x, lane = tid & 63, wave = tid >> 6;
  int wm = (wave >> 1) * 64, wn = (wave & 1) * 64;
  f32x4 acc[4][4] = {};
  int srow = tid >> 3;
  int sslot = tid & 7;

  for (int k0 = 0; k0 < 512; k0 += 64) {
    __syncthreads();
#pragma unroll
    for (int i = 0; i < 4; ++i) {
      int r = srow + 32 * i;
      int sw = (sslot ^ (r & 7)) * 8;
      u16x8 va = *reinterpret_cast<const u16x8*>(Ab + (size_t)(m0 + r) * 512 + k0 + sslot * 8);
      *reinterpret_cast<u16x8*>(&lA[r * 64 + sw]) = va;
      u16x8 vb = *reinterpret_cast<const u16x8*>(Bb + (size_t)(n0 + r) * 512 + k0 + sslot * 8);
      *reinterpret_cast<u16x8*>(&lB[r * 64 + sw]) = vb;
    }
    __syncthreads();
#pragma unroll
    for (int c = 0; c < 2; ++c) {
      bf16x8 af[4], bfr[4];
#pragma unroll
      for (int t = 0; t < 4; ++t) {
        int ra = wm + t * 16 + (lane & 15);
        int sa = (lane >> 4) + 4 * c;
        af[t] = ldfrag(&lA[ra * 64 + ((sa ^ (ra & 7)) * 8)]);
        int rb = wn + t * 16 + (lane & 15);
        bfr[t] = ldfrag(&lB[rb * 64 + ((sa ^ (rb & 7)) * 8)]);
      }
#pragma unroll
      for (int i = 0; i < 4; ++i)
#pragma unroll
        for (int j = 0; j < 4; ++j)
          acc[i][j] = MFMA(af[i], bfr[j], acc[i][j]);
    }
  }
  int row4 = (lane >> 4) * 4, col = lane & 15;
#pragma unroll
  for (int i = 0; i < 4; ++i)
#pragma unroll
    for (int j = 0; j < 4; ++j)
#pragma unroll
      for (int e = 0; e < 4; ++e) {
        int r = m0 + wm + i * 16 + row4 + e;
        int cN = n0 + wn + j * 16 + col;
        float v = acc[i][j][e] * scale;
        if (HAS_BIAS) v += bias[r];
        size_t idx = (size_t)b * sO + (size_t)r * N + cN;
        if (OUT_BF16) ((unsigned short*)Out)[idx] = f2bf(v);
        else          ((float*)Out)[idx] = v;
      }
}

// ---------------- fused attention: scores -> softmax -> A out + PV ----------------
// Qt,Kt: (B,L,512) bf16 (Q pre-scaled 0.125*log2e). Vn: (B,512,L) bf16.
// HhT out: (B,L,512) bf16. Aout: (B,H,L,L) f32.
// R1-proven structure + register ping-pong K prefetch (2-iter unroll) and
// 2^x softmax. No inter-wave coupling, no barriers.
__global__ __launch_bounds__(256) void k_attn(
    const unsigned short* __restrict__ Qt,
    const unsigned short* __restrict__ Kt,
    const unsigned short* __restrict__ Vn,
    unsigned short* __restrict__ HhT,
    float* __restrict__ Aout) {
  __shared__ __align__(16) unsigned short al[4][1024];  // per-wave 16x64 bf16, XOR-swizzled
  int bh = blockIdx.y;
  int b = bh >> 3, h = bh & 7;
  int lane = threadIdx.x & 63, wave = threadIdx.x >> 6;
  int q0 = blockIdx.x * 64 + wave * 16;
  const unsigned short* Qh = Qt + (size_t)b * L_SEQ * CDIM + h * DKH;
  const unsigned short* Kh = Kt + (size_t)b * L_SEQ * CDIM + h * DKH;
  const unsigned short* Vh = Vn + (size_t)b * CDIM * L_SEQ + (size_t)h * DKH * L_SEQ;
  unsigned short* Ho = HhT + (size_t)b * L_SEQ * CDIM + h * DKH;
  float* Ab = Aout + (size_t)bh * L_SEQ * L_SEQ;

  int fr = lane & 15, fg = lane >> 4;
  bf16x8 qf0 = ldfrag(Qh + (size_t)(q0 + fr) * CDIM + fg * 8);
  bf16x8 qf1 = ldfrag(Qh + (size_t)(q0 + fr) * CDIM + fg * 8 + 32);

  const unsigned short* kbase = Kh + (size_t)fr * CDIM + fg * 8;
  const unsigned short* vbase = Vh + (size_t)fr * L_SEQ + fg * 8;

  // -------- pass 1: row sums of 2^s (ping-pong K prefetch) --------
  float psum[4] = {0.f, 0.f, 0.f, 0.f};
  {
    u16x8 ka[8], kb2[8];
    auto half1 = [&](const u16x8* ks) {
#pragma unroll
      for (int t = 0; t < 4; ++t) {
        f32x4 s = {0.f, 0.f, 0.f, 0.f};
        s = MFMA(qf0, asbf(ks[2*t]), s);
        s = MFMA(qf1, asbf(ks[2*t+1]), s);
#pragma unroll
        for (int e = 0; e < 4; ++e) psum[e] += fexp2(s[e]);
      }
    };
    loadset(ka, kbase, 0, CDIM);
    for (int i = 0; i < 32; i += 2) {
      loadset(kb2, kbase, (i + 1) * 64, CDIM);
      half1(ka);
      loadset(ka, kbase, ((i + 2) & 31) * 64, CDIM);  // wraps on last iter, discarded
      half1(kb2);
    }
  }
#pragma unroll
  for (int e = 0; e < 4; ++e) {
    psum[e] += __shfl_xor(psum[e], 1, 64);
    psum[e] += __shfl_xor(psum[e], 2, 64);
    psum[e] += __shfl_xor(psum[e], 4, 64);
    psum[e] += __shfl_xor(psum[e], 8, 64);
  }
  float inv[4];
#pragma unroll
  for (int e = 0; e < 4; ++e) inv[e] = 1.0f / psum[e];

  // -------- pass 2: recompute, write A, accumulate PV --------
  f32x4 oacc[4] = {};
  unsigned short* alw = al[wave];
  {
    u16x8 ka[8], kb2[8];
    auto half2 = [&](const u16x8* ks, int kt) {
      // V frags for this half (loaded early, consumed at the bottom)
      u16x8 vr[8];
      loadset(vr, vbase, 0, 0);  // placeholder overwritten below (keeps type)
#pragma unroll
      for (int nt = 0; nt < 4; ++nt) {
        const unsigned short* vp = vbase + (size_t)(nt * 16) * L_SEQ + kt;
        vr[2*nt]   = *reinterpret_cast<const u16x8*>(vp);
        vr[2*nt+1] = *reinterpret_cast<const u16x8*>(vp + 32);
      }
      // QK^T + exp -> swizzled per-wave LDS (bf16)
#pragma unroll
      for (int t = 0; t < 4; ++t) {
        f32x4 s = {0.f, 0.f, 0.f, 0.f};
        s = MFMA(qf0, asbf(ks[2*t]), s);
        s = MFMA(qf1, asbf(ks[2*t+1]), s);
#pragma unroll
        for (int e = 0; e < 4; ++e) {
          float a = fexp2(s[e]) * inv[e];
          int row = fg * 4 + e;
          int byte = (row * 128 + (t * 16 + fr) * 2) ^ ((row & 7) << 4);
          alw[byte >> 1] = f2bf(a);
        }
      }
      // coalesced global A write from LDS
      {
        int wrow = lane >> 2;
        int slot0 = (lane & 3) * 2;
        int by0 = (wrow * 128 + slot0 * 16) ^ ((wrow & 7) << 4);
        int by1 = (wrow * 128 + (slot0 + 1) * 16) ^ ((wrow & 7) << 4);
        u16x8 p0 = *reinterpret_cast<const u16x8*>(alw + (by0 >> 1));
        u16x8 p1 = *reinterpret_cast<const u16x8*>(alw + (by1 >> 1));
        float* dp = Ab + (size_t)(q0 + wrow) * L_SEQ + kt + (lane & 3) * 16;
        f32x4 f0 = {bf2f(p0[0]), bf2f(p0[1]), bf2f(p0[2]), bf2f(p0[3])};
        f32x4 f1 = {bf2f(p0[4]), bf2f(p0[5]), bf2f(p0[6]), bf2f(p0[7])};
        f32x4 f2 = {bf2f(p1[0]), bf2f(p1[1]), bf2f(p1[2]), bf2f(p1[3])};
        f32x4 f3 = {bf2f(p1[4]), bf2f(p1[5]), bf2f(p1[6]), bf2f(p1[7])};
        *reinterpret_cast<f32x4*>(dp + 0)  = f0;
        *reinterpret_cast<f32x4*>(dp + 4)  = f1;
        *reinterpret_cast<f32x4*>(dp + 8)  = f2;
        *reinterpret_cast<f32x4*>(dp + 12) = f3;
      }
      // PV: A-frags from LDS, V-frags from regs
      int byA0 = (fr * 128 + fg * 16) ^ ((fr & 7) << 4);
      int byA1 = (fr * 128 + (fg + 4) * 16) ^ ((fr & 7) << 4);
      bf16x8 af0 = ldfrag(alw + (byA0 >> 1));
      bf16x8 af1 = ldfrag(alw + (byA1 >> 1));
#pragma unroll
      for (int nt = 0; nt < 4; ++nt) {
        oacc[nt] = MFMA(af0, asbf(vr[2*nt]), oacc[nt]);
        oacc[nt] = MFMA(af1, asbf(vr[2*nt+1]), oacc[nt]);
      }
    };
    loadset(ka, kbase, 0, CDIM);
    for (int i = 0; i < 32; i += 2) {
      loadset(kb2, kbase, (i + 1) * 64, CDIM);
      half2(ka, i * 64);
      loadset(ka, kbase, ((i + 2) & 31) * 64, CDIM);  // wraps on last iter, discarded
      half2(kb2, (i + 1) * 64);
    }
  }
  // write HhT (B,L,512) bf16
#pragma unroll
  for (int nt = 0; nt < 4; ++nt)
#pragma unroll
    for (int e = 0; e < 4; ++e)
      Ho[(size_t)(q0 + fg * 4 + e) * CDIM + nt * 16 + fr] = f2bf(oacc[nt][e]);
}

extern "C" void kernel_launch(void* const* d_in, const int* in_sizes, int n_in,
                              void* d_out, int out_size, void* d_ws, size_t ws_size,
                              hipStream_t stream) {
  const float* Xq = (const float*)d_in[0];
  const float* Xk = (const float*)d_in[1];
  const float* Xv = (const float*)d_in[2];
  const float* Wq = (const float*)d_in[3];
  const float* Wk = (const float*)d_in[4];
  const float* Wv = (const float*)d_in[5];
  const float* Wh = (const float*)d_in[6];
  const float* bh = (const float*)d_in[7];

  const size_t PROJ = (size_t)NB * L_SEQ * CDIM;
  float* out_f = (float*)d_out;
  float* A_out = out_f + PROJ;

  unsigned short* Qt = (unsigned short*)d_out;
  unsigned short* Kt = Qt + PROJ;
  unsigned short* Xtq = (unsigned short*)A_out;
  unsigned short* Xtk = Xtq + PROJ;
  unsigned short* Xtv = Xtk + PROJ;
  unsigned short* Vn  = (unsigned short*)d_ws;
  unsigned short* HhT = Vn + PROJ;
  unsigned short* Wqb = HhT + PROJ;
  unsigned short* Wkb = Wqb + CDIM * CDIM;
  unsigned short* Wvb = Wkb + CDIM * CDIM;
  unsigned short* Whb = Wvb + CDIM * CDIM;

  int nW = CDIM * CDIM;
  k_cast<<<nW / 2048, 256, 0, stream>>>(Wq, Wqb, nW);
  k_cast<<<nW / 2048, 256, 0, stream>>>(Wk, Wkb, nW);
  k_cast<<<nW / 2048, 256, 0, stream>>>(Wv, Wvb, nW);
  k_cast<<<nW / 2048, 256, 0, stream>>>(Wh, Whb, nW);

  dim3 tg(L_SEQ / 64, CDIM / 64, NB);
  k_transpose<<<tg, 256, 0, stream>>>(Xq, Xtq);
  k_transpose<<<tg, 256, 0, stream>>>(Xk, Xtk);
  k_transpose<<<tg, 256, 0, stream>>>(Xv, Xtv);

  const long sLC = (long)L_SEQ * CDIM;
  // Qt = Xtq . Wq^T * (0.125 * log2(e))  -> softmax uses 2^x
  k_gemm_nt<1, 0><<<dim3(CDIM / 128, L_SEQ / 128, NB), 256, 0, stream>>>(
      Xtq, sLC, Wqb, 0, Qt, sLC, nullptr, 0.18033688f, L_SEQ, CDIM);
  k_gemm_nt<1, 0><<<dim3(CDIM / 128, L_SEQ / 128, NB), 256, 0, stream>>>(
      Xtk, sLC, Wkb, 0, Kt, sLC, nullptr, 1.0f, L_SEQ, CDIM);
  k_gemm_nt<1, 0><<<dim3(L_SEQ / 128, CDIM / 128, NB), 256, 0, stream>>>(
      Wvb, 0, Xtv, sLC, Vn, sLC, nullptr, 1.0f, CDIM, L_SEQ);

  k_attn<<<dim3(L_SEQ / 64, NB * NH), 256, 0, stream>>>(Qt, Kt, Vn, HhT, A_out);

  k_gemm_nt<0, 1><<<dim3(L_SEQ / 128, CDIM / 128, NB), 256, 0, stream>>>(
      Whb, 0, HhT, sLC, out_f, sLC, bh, 1.0f, CDIM, L_SEQ);
}